// Round 13
// baseline (1215.181 us; speedup 1.0000x reference)
//
#include <hip/hip_runtime.h>
#include <hip/hip_bf16.h>
#include <cstdint>

#define HDIM 256
#define H2   128
#define BCAP 4608     // bucket capacity (entries), mean 4096, +8 sigma
#define SCAP 4608     // csr-span LDS staging capacity (ints)

using f32x4  = __attribute__((ext_vector_type(4))) float;
using bf16x8 = __attribute__((ext_vector_type(8))) short;    // 8 bf16 in 4 VGPRs
using u16x8  = __attribute__((ext_vector_type(8))) unsigned short;

__device__ inline unsigned short f2bf(float f) {             // round-to-nearest-even
    unsigned x = __builtin_bit_cast(unsigned, f);
    return (unsigned short)((x + 0x7fffu + ((x >> 16) & 1u)) >> 16);
}
__device__ inline float bf2f(unsigned short u) {
    unsigned x = ((unsigned)u) << 16;
    return __builtin_bit_cast(float, x);
}

// ---------------------------------------------------------------------------
// Pass A: in-degree count + bucket append (bucket = dest >> 8).
// Buckets localize the later csr scatter; appends are 8B into ~391 streams,
// killing k_fill's 17x line write-amp (107MB writes for a 6.4MB buffer).
__global__ void k_bucket(const int* __restrict__ row, const int* __restrict__ col,
                         int* __restrict__ deg0, int* __restrict__ bcur,
                         unsigned long long* __restrict__ buckets, int e) {
    int i = blockIdx.x * blockDim.x + threadIdx.x;
    if (i >= e) return;
    int c = col[i], r = row[i];
    atomicAdd(&deg0[c], 1);
    int b = c >> 8;
    int s = atomicAdd(&bcur[b], 1);
    if (s < BCAP)
        buckets[(size_t)b * BCAP + s] = ((unsigned long long)(unsigned)r << 32) | (unsigned)c;
}

__global__ void k_scan1(const int* __restrict__ deg0, int* __restrict__ ptr,
                        int* __restrict__ bsum, int n) {
    __shared__ int sd[256];
    int i = blockIdx.x * 256 + threadIdx.x;
    int v = (i < n) ? deg0[i] : 0;
    sd[threadIdx.x] = v;
    __syncthreads();
    for (int off = 1; off < 256; off <<= 1) {
        int t = (threadIdx.x >= off) ? sd[threadIdx.x - off] : 0;
        __syncthreads();
        sd[threadIdx.x] += t;
        __syncthreads();
    }
    if (i < n) ptr[i] = sd[threadIdx.x] - v;
    if (threadIdx.x == 255) bsum[blockIdx.x] = sd[255];
}

__global__ void k_scan2(int* __restrict__ bsum, int nb) {
    __shared__ int sd[512];
    int t = threadIdx.x;
    int v = (t < nb) ? bsum[t] : 0;
    sd[t] = v;
    __syncthreads();
    for (int off = 1; off < 512; off <<= 1) {
        int x = (t >= off) ? sd[t - off] : 0;
        __syncthreads();
        sd[t] += x;
        __syncthreads();
    }
    if (t < nb) bsum[t] = sd[t] - v;
}

// scan finalize + dis = (deg0+1)^-0.5 (self-loop included in norm)
__global__ void k_scan3(int* __restrict__ ptr, const int* __restrict__ bsum,
                        const int* __restrict__ deg0, float* __restrict__ dis, int n) {
    int i = blockIdx.x * 256 + threadIdx.x;
    if (i < n) {
        ptr[i] += bsum[blockIdx.x];
        dis[i] = rsqrtf((float)deg0[i] + 1.0f);
    }
}

// Pass B: block per bucket. Counting-sort the bucket's entries through LDS
// (per-node LDS cursors), then write the bucket's CONTIGUOUS csr span
// coalesced. csr writes go from 17x-amplified random 4B to sequential 16B+.
__global__ __launch_bounds__(256) void k_sort(const unsigned long long* __restrict__ buckets,
                                              const int* __restrict__ bcur,
                                              const int* __restrict__ ptr,
                                              int* __restrict__ csr,
                                              int n, int etot) {
    __shared__ int stage[SCAP];
    __shared__ int lcur[256];
    int b = blockIdx.x, t = threadIdx.x;
    int v0 = b << 8;
    int v1 = v0 + 256; if (v1 > n) v1 = n;
    lcur[t] = 0;
    __syncthreads();
    int base = ptr[v0];
    int end  = (v1 < n) ? ptr[v1] : etot;
    int span = end - base; if (span > SCAP) span = SCAP;
    int bc = bcur[b]; if (bc > BCAP) bc = BCAP;
    for (int i = t; i < bc; i += 256) {
        unsigned long long en = buckets[(size_t)b * BCAP + i];
        int c = (int)(en & 0xffffffffu);
        int r = (int)(en >> 32);
        int off = atomicAdd(&lcur[c & 255], 1);
        int pos = ptr[c] - base + off;
        if (pos < SCAP) stage[pos] = r;
    }
    __syncthreads();
    for (int j = t; j < span; j += 256) csr[base + j] = stage[j];
}

// convert atom-embedding table fp32 -> bf16 (F*V*HDIM = ~295K elems, 1.2MB)
__global__ void k_emb(const float* __restrict__ emb, short* __restrict__ embb, int tot) {
    int i = blockIdx.x * 256 + threadIdx.x;
    if (i < tot) embb[i] = (short)f2bf(emb[i]);
}

// AtomEncoder from bf16 table (L2-resident): wave per node, lane = 4 cols
__global__ __launch_bounds__(256) void k_atom(const int* __restrict__ x,
                                              const short* __restrict__ embb,
                                              short* __restrict__ h,
                                              int n, int F, int V) {
    int node = blockIdx.x * 4 + (threadIdx.x >> 6);
    int lane = threadIdx.x & 63;
    if (node >= n) return;
    int xv = x[node * F + (lane < F ? lane : 0)];
    float acc[4] = {};
    for (int f = 0; f < F; ++f) {
        int idx = __shfl(xv, f, 64);
        ushort4 v = *(const ushort4*)((const unsigned short*)embb +
                                      ((size_t)(f * V + idx)) * HDIM + lane * 4);
        acc[0] += bf2f(v.x); acc[1] += bf2f(v.y);
        acc[2] += bf2f(v.z); acc[3] += bf2f(v.w);
    }
    ushort4 o = { f2bf(acc[0]), f2bf(acc[1]), f2bf(acc[2]), f2bf(acc[3]) };
    *(ushort4*)(h + (size_t)node * HDIM + lane * 4) = o;
}

// transpose + convert all three W (fp32 [K][N]) -> Wt (bf16 [N][K]); grid.y = layer
__global__ void k_wt3(const float* __restrict__ W1, const float* __restrict__ W2,
                      const float* __restrict__ W3, short* __restrict__ Wt1,
                      short* __restrict__ Wt2, short* __restrict__ Wt3) {
    const float* W = (blockIdx.y == 0) ? W1 : (blockIdx.y == 1) ? W2 : W3;
    short* Wt      = (blockIdx.y == 0) ? Wt1 : (blockIdx.y == 1) ? Wt2 : Wt3;
    int i = blockIdx.x * 256 + threadIdx.x;
    int nn = i >> 8, k = i & 255;
    Wt[nn * HDIM + k] = (short)f2bf(W[k * HDIM + nn]);
}

// bf16 MFMA GEMM: C[n,256] = A[n,256] @ W, Wt = W^T bf16.
// 64-row tiles, 256 threads = 4 col-waves, 32KB LDS, 4 blocks/CU.
// A staged via global_load_lds w16; linear LDS dest + inverse-swizzled global
// source; reads XOR ((row&7)<<4).
__global__ __launch_bounds__(256, 4) void k_gemm(const short* __restrict__ A,
                                                 const short* __restrict__ Wt,
                                                 short* __restrict__ Co, int n) {
    __shared__ unsigned char As[64 * 512];     // 32 KB
    int row0 = blockIdx.x * 64;
    int t = threadIdx.x;
    int wid  = t >> 6;
    int lane = t & 63;
#pragma unroll
    for (int j = 0; j < 8; ++j) {
        int c  = (wid * 8 + j) * 64 + lane;       // 16B chunk index 0..2047
        int r  = c >> 5;                          // tile row 0..63
        int cb = (c & 31) * 16;                   // byte within row
        int gr = row0 + r; if (gr >= n) gr = n - 1;
        const unsigned int* g = (const unsigned int*)
            ((const char*)A + (size_t)gr * 512 + (cb ^ ((r & 7) << 4)));
        unsigned int* l = (unsigned int*)(As + (size_t)(wid * 8 + j) * 1024);
        __builtin_amdgcn_global_load_lds(g, l, 16, 0, 0);
    }
    __syncthreads();

    int lm = lane & 15;
    int kg = lane >> 4;
    int colw = wid * 64;                          // each wave owns 64 cols
    f32x4 acc[4][4] = {};
#pragma unroll 2
    for (int kk = 0; kk < 8; ++kk) {              // k-chunk of 32 elems (64 B)
        bf16x8 a[4], b[4];
#pragma unroll
        for (int i = 0; i < 4; ++i) {
            int R = i * 16 + lm;
            int boff = (kk * 64 + kg * 16) ^ ((R & 7) << 4);
            a[i] = *(const bf16x8*)(As + R * 512 + boff);
        }
#pragma unroll
        for (int j = 0; j < 4; ++j) {
            int cidx = colw + j * 16 + lm;
            b[j] = *(const bf16x8*)(Wt + (size_t)cidx * HDIM + kk * 32 + kg * 8);
        }
#pragma unroll
        for (int i = 0; i < 4; ++i)
#pragma unroll
            for (int j = 0; j < 4; ++j)
                acc[i][j] = __builtin_amdgcn_mfma_f32_16x16x32_bf16(a[i], b[j], acc[i][j], 0, 0, 0);
    }
#pragma unroll
    for (int i = 0; i < 4; ++i)
#pragma unroll
        for (int j = 0; j < 4; ++j) {
            int c = colw + j * 16 + lm;
#pragma unroll
            for (int r4 = 0; r4 < 4; ++r4) {
                int r = row0 + i * 16 + kg * 4 + r4;
                if (r < n) Co[(size_t)r * HDIM + c] = (short)f2bf(acc[i][j][r4]);
            }
        }
}

// gather-aggregate: wave per node, supersteps of 8 edges with 4 independent
// row loads in flight per lane. 32 lanes x ushort8 = one 512B message row;
// halves split even/odd edges; final xor-32 reduce merges them.
// Structurally pinned at L2-miss/L3 path ~3.9 TB/s (R6-R12: ~123us, FETCH 417MB).
__global__ __launch_bounds__(256) void k_agg(const short* __restrict__ mS,
                                             const int* __restrict__ csr_src,
                                             const int* __restrict__ ptr,
                                             const int* __restrict__ deg0,
                                             const float* __restrict__ dis,
                                             const float* __restrict__ bias,
                                             short* __restrict__ xout, int n) {
    int node = blockIdx.x * 4 + (threadIdx.x >> 6);
    if (node >= n) return;
    int lane = threadIdx.x & 63;
    int half = lane >> 5;
    int cl = lane & 31;                       // col group: 8 cols
    const unsigned short* m = (const unsigned short*)mS;
    float dv = dis[node];
    float acc[8] = {};
    if (half == 0) {                          // self-loop term
        u16x8 r = *(const u16x8*)(m + (size_t)node * HDIM + cl * 8);
        float sw = dv * dv;
#pragma unroll
        for (int j = 0; j < 8; ++j) acc[j] = sw * bf2f(r[j]);
    }
    int start = ptr[node];
    int cnt = deg0[node];
    for (int base = 0; base < cnt; base += 64) {
        int mm = cnt - base; if (mm > 64) mm = 64;
        int uu = 0; float du = 0.f;
        if (lane < mm) {
            uu = __builtin_nontemporal_load(&csr_src[start + base + lane]);
            du = dis[uu];
        }
        int nst = (mm + 7) >> 3;              // supersteps of 8 edges (4/half)
        for (int s = 0; s < nst; ++s) {
            u16x8 r[4]; float w[4];
#pragma unroll
            for (int q = 0; q < 4; ++q) {     // issue 4 independent loads
                int i = 8 * s + 2 * q + half;
                int u   = __shfl(uu, i & 63, 64);
                float ww = dv * __shfl(du, i & 63, 64);
                bool v = i < mm;
                w[q] = v ? ww : 0.f;
                r[q] = *(const u16x8*)(m + (size_t)(v ? u : 0) * HDIM + cl * 8);
            }
#pragma unroll
            for (int q = 0; q < 4; ++q)
#pragma unroll
                for (int j = 0; j < 8; ++j) acc[j] += w[q] * bf2f(r[q][j]);
        }
    }
#pragma unroll
    for (int j = 0; j < 8; ++j) acc[j] += __shfl_xor(acc[j], 32, 64);
    if (half == 0) {
        const float4 b0 = *(const float4*)(bias + cl * 8);
        const float4 b1 = *(const float4*)(bias + cl * 8 + 4);
        float bb[8] = {b0.x, b0.y, b0.z, b0.w, b1.x, b1.y, b1.z, b1.w};
        u16x8 o;
#pragma unroll
        for (int j = 0; j < 8; ++j)
            o[j] = f2bf(fmaxf(acc[j] + bb[j], 0.f));
        *(u16x8*)((unsigned short*)xout + (size_t)node * HDIM + cl * 8) = o;
    }
}

// pooling, partial-sum form (atomic-free): grid (B, 4). Block (g, seg) sums
// its quarter of graph g's rows over x1+x2+x3 -> partial[(seg*B+g)*HDIM+t].
__global__ __launch_bounds__(256) void k_pool(const short* __restrict__ x1,
                                              const short* __restrict__ x2,
                                              const short* __restrict__ x3,
                                              const int* __restrict__ batch,
                                              float* __restrict__ partial,
                                              int n, int B) {
    __shared__ float spool[8][HDIM];
    int g = blockIdx.x, seg = blockIdx.y, t = threadIdx.x;
    int cg = t & 31, rl = t >> 5;
    auto lb = [&](int key) {
        int lo = 0, hi = n;
        while (lo < hi) { int mid = (lo + hi) >> 1; if (batch[mid] < key) lo = mid + 1; else hi = mid; }
        return lo;
    };
    int lo = lb(g), hi = lb(g + 1);
    int len = hi - lo;
    int per = (len + 3) >> 2;
    int s0 = lo + seg * per;
    int s1 = s0 + per; if (s1 > hi) s1 = hi;
    float acc[8] = {};
    for (int r = s0 + rl; r < s1; r += 8) {
        size_t base = (size_t)r * HDIM + cg * 8;
        u16x8 a = *(const u16x8*)((const unsigned short*)x1 + base);
        u16x8 b = *(const u16x8*)((const unsigned short*)x2 + base);
        u16x8 c = *(const u16x8*)((const unsigned short*)x3 + base);
#pragma unroll
        for (int j = 0; j < 8; ++j)
            acc[j] += bf2f(a[j]) + bf2f(b[j]) + bf2f(c[j]);
    }
#pragma unroll
    for (int j = 0; j < 8; ++j) spool[rl][cg * 8 + j] = acc[j];
    __syncthreads();
    float s = 0.f;
#pragma unroll
    for (int r2 = 0; r2 < 8; ++r2) s += spool[r2][t];
    partial[(size_t)(seg * B + g) * HDIM + t] = s;
}

// classifier: sum 4 partials, divide by count (binary search), 2-layer MLP.
__global__ __launch_bounds__(256) void k_cls(const float* __restrict__ partial,
                                             const int* __restrict__ batch,
                                             const float* __restrict__ cw1,
                                             const float* __restrict__ cb1,
                                             const float* __restrict__ cw2,
                                             const float* __restrict__ cb2,
                                             float* __restrict__ out,
                                             int n, int B, int C) {
    __shared__ float sp[HDIM];
    __shared__ float sh[H2];
    int g = blockIdx.x, t = threadIdx.x;
    auto lb = [&](int key) {
        int lo = 0, hi = n;
        while (lo < hi) { int mid = (lo + hi) >> 1; if (batch[mid] < key) lo = mid + 1; else hi = mid; }
        return lo;
    };
    int lo = lb(g), hi = lb(g + 1);
    int cnt = hi - lo; if (cnt < 1) cnt = 1;
    float s = 0.f;
#pragma unroll
    for (int seg = 0; seg < 4; ++seg)
        s += partial[(size_t)(seg * B + g) * HDIM + t];
    sp[t] = s / (float)cnt;
    __syncthreads();
    if (t < H2) {
        float a = cb1[t];
        for (int h = 0; h < HDIM; ++h) a += sp[h] * cw1[h * H2 + t];
        sh[t] = fmaxf(a, 0.f);
    }
    __syncthreads();
    if (t < C) {
        float o = cb2[t];
        for (int j = 0; j < H2; ++j) o += sh[j] * cw2[j * C + t];
        out[g * C + t] = o;
    }
    if (g == 0 && t == 0) out[B * C] = 0.f;
}

// ---------------------------------------------------------------------------
extern "C" void kernel_launch(void* const* d_in, const int* in_sizes, int n_in,
                              void* d_out, int out_size, void* d_ws, size_t ws_size,
                              hipStream_t stream) {
    const int* x      = (const int*)d_in[0];
    const int* erow   = (const int*)d_in[1];
    const int* batch  = (const int*)d_in[2];
    const float* emb  = (const float*)d_in[3];
    const float* W1   = (const float*)d_in[4];
    const float* b1   = (const float*)d_in[5];
    const float* W2   = (const float*)d_in[6];
    const float* b2   = (const float*)d_in[7];
    const float* W3   = (const float*)d_in[8];
    const float* b3   = (const float*)d_in[9];
    const float* cw1  = (const float*)d_in[10];
    const float* cb1  = (const float*)d_in[11];
    const float* cw2  = (const float*)d_in[12];
    const float* cb2  = (const float*)d_in[13];
    float* out = (float*)d_out;

    const int N = in_sizes[2];
    const int E = in_sizes[1] / 2;
    const int F = in_sizes[0] / N;
    const int V = in_sizes[3] / (F * HDIM);
    const int C = in_sizes[13];
    const int B = (out_size - 1) / C;
    const int* ecol = erow + E;
    const int EMBTOT = F * V * HDIM;
    const int NB = (N + 255) >> 8;          // buckets (dest range = 256 nodes)

    char* w = (char*)d_ws;
    auto carve = [&](size_t bytes) {
        void* p = (void*)w;
        w += (bytes + 255) & ~(size_t)255;
        return p;
    };
    short* P0     = (short*)carve((size_t)N * HDIM * 2);   // h0, later x3
    short* P1     = (short*)carve((size_t)N * HDIM * 2);   // x1
    short* P2     = (short*)carve((size_t)N * HDIM * 2);   // x2
    short* mS     = (short*)carve((size_t)N * HDIM * 2);   // GEMM output (messages)
    short* embb   = (short*)carve((size_t)EMBTOT * 2);
    short* Wt1    = (short*)carve((size_t)HDIM * HDIM * 2);
    short* Wt2    = (short*)carve((size_t)HDIM * HDIM * 2);
    short* Wt3    = (short*)carve((size_t)HDIM * HDIM * 2);
    float* partial= (float*)carve((size_t)4 * B * HDIM * 4);
    float* dis    = (float*)carve((size_t)N * 4);
    int* deg0     = (int*)carve((size_t)N * 4);
    int* ptr      = (int*)carve((size_t)N * 4);
    int* bcur     = (int*)carve((size_t)NB * 4);
    int* bsum     = (int*)carve(1024 * 4);
    int* csr      = (int*)carve((size_t)E * 4);
    unsigned long long* buckets =
        (unsigned long long*)carve((size_t)NB * BCAP * 8);

    int nblk = (N + 255) / 256;

    hipMemsetAsync(deg0, 0, (size_t)N * 4, stream);
    hipMemsetAsync(bcur, 0, (size_t)NB * 4, stream);
    k_bucket<<<(E + 255) / 256, 256, 0, stream>>>(erow, ecol, deg0, bcur, buckets, E);
    k_scan1<<<nblk, 256, 0, stream>>>(deg0, ptr, bsum, N);
    k_scan2<<<1, 512, 0, stream>>>(bsum, nblk);
    k_scan3<<<nblk, 256, 0, stream>>>(ptr, bsum, deg0, dis, N);
    k_sort<<<NB, 256, 0, stream>>>(buckets, bcur, ptr, csr, N, E);
    k_emb<<<(EMBTOT + 255) / 256, 256, 0, stream>>>(emb, embb, EMBTOT);
    dim3 wgrid(HDIM, 3);
    k_wt3<<<wgrid, 256, 0, stream>>>(W1, W2, W3, Wt1, Wt2, Wt3);
    k_atom<<<(N + 3) / 4, 256, 0, stream>>>(x, embb, P0, N, F, V);

    int ggrid = (N + 63) / 64;
    int agrid = (N + 3) / 4;

    k_gemm<<<ggrid, 256, 0, stream>>>(P0, Wt1, mS, N);
    k_agg<<<agrid, 256, 0, stream>>>(mS, csr, ptr, deg0, dis, b1, P1, N);
    k_gemm<<<ggrid, 256, 0, stream>>>(P1, Wt2, mS, N);
    k_agg<<<agrid, 256, 0, stream>>>(mS, csr, ptr, deg0, dis, b2, P2, N);
    k_gemm<<<ggrid, 256, 0, stream>>>(P2, Wt3, mS, N);
    k_agg<<<agrid, 256, 0, stream>>>(mS, csr, ptr, deg0, dis, b3, P0, N);

    dim3 pgrid(B, 4);
    k_pool<<<pgrid, 256, 0, stream>>>(P1, P2, P0, batch, partial, N, B);
    k_cls<<<B, 256, 0, stream>>>(partial, batch, cw1, cb1, cw2, cb2, out, N, B, C);
}

// Round 14
// 726.729 us; speedup vs baseline: 1.6721x; 1.6721x over previous
//
#include <hip/hip_runtime.h>
#include <hip/hip_bf16.h>
#include <cstdint>

#define HDIM 256
#define H2   128

using f32x4  = __attribute__((ext_vector_type(4))) float;
using bf16x8 = __attribute__((ext_vector_type(8))) short;    // 8 bf16 in 4 VGPRs
using u16x8  = __attribute__((ext_vector_type(8))) unsigned short;

__device__ inline unsigned short f2bf(float f) {             // round-to-nearest-even
    unsigned x = __builtin_bit_cast(unsigned, f);
    return (unsigned short)((x + 0x7fffu + ((x >> 16) & 1u)) >> 16);
}
__device__ inline float bf2f(unsigned short u) {
    unsigned x = ((unsigned)u) << 16;
    return __builtin_bit_cast(float, x);
}

// ---------------------------------------------------------------------------
// deg0 = in-degree WITHOUT self-loop (buffer memset to 0 before)
__global__ void k_deg(const int* __restrict__ col, int* __restrict__ deg0, int e) {
    int i = blockIdx.x * blockDim.x + threadIdx.x;
    if (i < e) atomicAdd(&deg0[col[i]], 1);
}

__global__ void k_scan1(const int* __restrict__ deg0, int* __restrict__ ptr,
                        int* __restrict__ bsum, int n) {
    __shared__ int sd[256];
    int i = blockIdx.x * 256 + threadIdx.x;
    int v = (i < n) ? deg0[i] : 0;
    sd[threadIdx.x] = v;
    __syncthreads();
    for (int off = 1; off < 256; off <<= 1) {
        int t = (threadIdx.x >= off) ? sd[threadIdx.x - off] : 0;
        __syncthreads();
        sd[threadIdx.x] += t;
        __syncthreads();
    }
    if (i < n) ptr[i] = sd[threadIdx.x] - v;
    if (threadIdx.x == 255) bsum[blockIdx.x] = sd[255];
}

__global__ void k_scan2(int* __restrict__ bsum, int nb) {
    __shared__ int sd[512];
    int t = threadIdx.x;
    int v = (t < nb) ? bsum[t] : 0;
    sd[t] = v;
    __syncthreads();
    for (int off = 1; off < 512; off <<= 1) {
        int x = (t >= off) ? sd[t - off] : 0;
        __syncthreads();
        sd[t] += x;
        __syncthreads();
    }
    if (t < nb) bsum[t] = sd[t] - v;
}

// scan finalize + dis = (deg0+1)^-0.5 (self-loop included in norm)
__global__ void k_scan3(int* __restrict__ ptr, const int* __restrict__ bsum,
                        const int* __restrict__ deg0, float* __restrict__ dis, int n) {
    int i = blockIdx.x * 256 + threadIdx.x;
    if (i < n) {
        ptr[i] += bsum[blockIdx.x];
        dis[i] = rsqrtf((float)deg0[i] + 1.0f);
    }
}

// CSR fill with XCD-affinity phasing. R12's k_fill: random 4B scatter makes
// each 64B csr line (~one node's list) bounce between 8 non-coherent L2s ->
// 17x write amp (107MB for 6.4MB), 124us. Here: grid = chunks x 8; block's
// xcd = blockIdx&7 (round-robin dispatch, validated R3/R5); block processes
// its 2048-edge chunk but writes ONLY dests with ((col>>3)&7)==xcd. All
// writes to a line then come from one XCD -> line built in its L2, written
// back once. ecol re-read 8x (51MB, L2/L3) is the cheap price.
__global__ __launch_bounds__(256) void k_fill8(const int* __restrict__ row,
                                               const int* __restrict__ col,
                                               const int* __restrict__ ptr,
                                               int* __restrict__ cursor,
                                               int* __restrict__ csr, int e) {
    int xcd   = blockIdx.x & 7;
    int chunk = blockIdx.x >> 3;
    int base  = chunk * 2048;
    int end   = base + 2048; if (end > e) end = e;
    for (int i = base + threadIdx.x; i < end; i += 256) {
        int c = col[i];
        if (((c >> 3) & 7) == xcd) {
            int s = atomicAdd(&cursor[c], 1);
            csr[ptr[c] + s] = row[i];
        }
    }
}

// convert atom-embedding table fp32 -> bf16 (F*V*HDIM = ~295K elems, 1.2MB)
__global__ void k_emb(const float* __restrict__ emb, short* __restrict__ embb, int tot) {
    int i = blockIdx.x * 256 + threadIdx.x;
    if (i < tot) embb[i] = (short)f2bf(emb[i]);
}

// AtomEncoder from bf16 table (L2-resident): wave per node, lane = 4 cols
__global__ __launch_bounds__(256) void k_atom(const int* __restrict__ x,
                                              const short* __restrict__ embb,
                                              short* __restrict__ h,
                                              int n, int F, int V) {
    int node = blockIdx.x * 4 + (threadIdx.x >> 6);
    int lane = threadIdx.x & 63;
    if (node >= n) return;
    int xv = x[node * F + (lane < F ? lane : 0)];
    float acc[4] = {};
    for (int f = 0; f < F; ++f) {
        int idx = __shfl(xv, f, 64);
        ushort4 v = *(const ushort4*)((const unsigned short*)embb +
                                      ((size_t)(f * V + idx)) * HDIM + lane * 4);
        acc[0] += bf2f(v.x); acc[1] += bf2f(v.y);
        acc[2] += bf2f(v.z); acc[3] += bf2f(v.w);
    }
    ushort4 o = { f2bf(acc[0]), f2bf(acc[1]), f2bf(acc[2]), f2bf(acc[3]) };
    *(ushort4*)(h + (size_t)node * HDIM + lane * 4) = o;
}

// transpose + convert all three W (fp32 [K][N]) -> Wt (bf16 [N][K]); grid.y = layer
__global__ void k_wt3(const float* __restrict__ W1, const float* __restrict__ W2,
                      const float* __restrict__ W3, short* __restrict__ Wt1,
                      short* __restrict__ Wt2, short* __restrict__ Wt3) {
    const float* W = (blockIdx.y == 0) ? W1 : (blockIdx.y == 1) ? W2 : W3;
    short* Wt      = (blockIdx.y == 0) ? Wt1 : (blockIdx.y == 1) ? Wt2 : Wt3;
    int i = blockIdx.x * 256 + threadIdx.x;
    int nn = i >> 8, k = i & 255;
    Wt[nn * HDIM + k] = (short)f2bf(W[k * HDIM + nn]);
}

// bf16 MFMA GEMM: C[n,256] = A[n,256] @ W, Wt = W^T bf16.
// 64-row tiles, 256 threads = 4 col-waves, 32KB LDS, 4 blocks/CU.
// A staged via global_load_lds w16; linear LDS dest + inverse-swizzled global
// source; reads XOR ((row&7)<<4). t_gemm ~= 45us (R11/R12 attribution).
__global__ __launch_bounds__(256, 4) void k_gemm(const short* __restrict__ A,
                                                 const short* __restrict__ Wt,
                                                 short* __restrict__ Co, int n) {
    __shared__ unsigned char As[64 * 512];     // 32 KB
    int row0 = blockIdx.x * 64;
    int t = threadIdx.x;
    int wid  = t >> 6;
    int lane = t & 63;
#pragma unroll
    for (int j = 0; j < 8; ++j) {
        int c  = (wid * 8 + j) * 64 + lane;       // 16B chunk index 0..2047
        int r  = c >> 5;                          // tile row 0..63
        int cb = (c & 31) * 16;                   // byte within row
        int gr = row0 + r; if (gr >= n) gr = n - 1;
        const unsigned int* g = (const unsigned int*)
            ((const char*)A + (size_t)gr * 512 + (cb ^ ((r & 7) << 4)));
        unsigned int* l = (unsigned int*)(As + (size_t)(wid * 8 + j) * 1024);
        __builtin_amdgcn_global_load_lds(g, l, 16, 0, 0);
    }
    __syncthreads();

    int lm = lane & 15;
    int kg = lane >> 4;
    int colw = wid * 64;                          // each wave owns 64 cols
    f32x4 acc[4][4] = {};
#pragma unroll 2
    for (int kk = 0; kk < 8; ++kk) {              // k-chunk of 32 elems (64 B)
        bf16x8 a[4], b[4];
#pragma unroll
        for (int i = 0; i < 4; ++i) {
            int R = i * 16 + lm;
            int boff = (kk * 64 + kg * 16) ^ ((R & 7) << 4);
            a[i] = *(const bf16x8*)(As + R * 512 + boff);
        }
#pragma unroll
        for (int j = 0; j < 4; ++j) {
            int cidx = colw + j * 16 + lm;
            b[j] = *(const bf16x8*)(Wt + (size_t)cidx * HDIM + kk * 32 + kg * 8);
        }
#pragma unroll
        for (int i = 0; i < 4; ++i)
#pragma unroll
            for (int j = 0; j < 4; ++j)
                acc[i][j] = __builtin_amdgcn_mfma_f32_16x16x32_bf16(a[i], b[j], acc[i][j], 0, 0, 0);
    }
#pragma unroll
    for (int i = 0; i < 4; ++i)
#pragma unroll
        for (int j = 0; j < 4; ++j) {
            int c = colw + j * 16 + lm;
#pragma unroll
            for (int r4 = 0; r4 < 4; ++r4) {
                int r = row0 + i * 16 + kg * 4 + r4;
                if (r < n) Co[(size_t)r * HDIM + c] = (short)f2bf(acc[i][j][r4]);
            }
        }
}

// gather-aggregate: wave per node, supersteps of 8 edges with 4 independent
// row loads in flight per lane. 32 lanes x ushort8 = one 512B message row;
// halves split even/odd edges; final xor-32 reduce merges them.
// Structurally pinned at L2-miss/L3 path ~3.9 TB/s (R6-R12: ~123us, FETCH 417MB).
__global__ __launch_bounds__(256) void k_agg(const short* __restrict__ mS,
                                             const int* __restrict__ csr_src,
                                             const int* __restrict__ ptr,
                                             const int* __restrict__ deg0,
                                             const float* __restrict__ dis,
                                             const float* __restrict__ bias,
                                             short* __restrict__ xout, int n) {
    int node = blockIdx.x * 4 + (threadIdx.x >> 6);
    if (node >= n) return;
    int lane = threadIdx.x & 63;
    int half = lane >> 5;
    int cl = lane & 31;                       // col group: 8 cols
    const unsigned short* m = (const unsigned short*)mS;
    float dv = dis[node];
    float acc[8] = {};
    if (half == 0) {                          // self-loop term
        u16x8 r = *(const u16x8*)(m + (size_t)node * HDIM + cl * 8);
        float sw = dv * dv;
#pragma unroll
        for (int j = 0; j < 8; ++j) acc[j] = sw * bf2f(r[j]);
    }
    int start = ptr[node];
    int cnt = deg0[node];
    for (int base = 0; base < cnt; base += 64) {
        int mm = cnt - base; if (mm > 64) mm = 64;
        int uu = 0; float du = 0.f;
        if (lane < mm) {
            uu = __builtin_nontemporal_load(&csr_src[start + base + lane]);
            du = dis[uu];
        }
        int nst = (mm + 7) >> 3;              // supersteps of 8 edges (4/half)
        for (int s = 0; s < nst; ++s) {
            u16x8 r[4]; float w[4];
#pragma unroll
            for (int q = 0; q < 4; ++q) {     // issue 4 independent loads
                int i = 8 * s + 2 * q + half;
                int u   = __shfl(uu, i & 63, 64);
                float ww = dv * __shfl(du, i & 63, 64);
                bool v = i < mm;
                w[q] = v ? ww : 0.f;
                r[q] = *(const u16x8*)(m + (size_t)(v ? u : 0) * HDIM + cl * 8);
            }
#pragma unroll
            for (int q = 0; q < 4; ++q)
#pragma unroll
                for (int j = 0; j < 8; ++j) acc[j] += w[q] * bf2f(r[q][j]);
        }
    }
#pragma unroll
    for (int j = 0; j < 8; ++j) acc[j] += __shfl_xor(acc[j], 32, 64);
    if (half == 0) {
        const float4 b0 = *(const float4*)(bias + cl * 8);
        const float4 b1 = *(const float4*)(bias + cl * 8 + 4);
        float bb[8] = {b0.x, b0.y, b0.z, b0.w, b1.x, b1.y, b1.z, b1.w};
        u16x8 o;
#pragma unroll
        for (int j = 0; j < 8; ++j)
            o[j] = f2bf(fmaxf(acc[j] + bb[j], 0.f));
        *(u16x8*)((unsigned short*)xout + (size_t)node * HDIM + cl * 8) = o;
    }
}

// pooling, partial-sum form (atomic-free): grid (B, 4). Block (g, seg) sums
// its quarter of graph g's rows over x1+x2+x3 -> partial[(seg*B+g)*HDIM+t].
__global__ __launch_bounds__(256) void k_pool(const short* __restrict__ x1,
                                              const short* __restrict__ x2,
                                              const short* __restrict__ x3,
                                              const int* __restrict__ batch,
                                              float* __restrict__ partial,
                                              int n, int B) {
    __shared__ float spool[8][HDIM];
    int g = blockIdx.x, seg = blockIdx.y, t = threadIdx.x;
    int cg = t & 31, rl = t >> 5;
    auto lb = [&](int key) {
        int lo = 0, hi = n;
        while (lo < hi) { int mid = (lo + hi) >> 1; if (batch[mid] < key) lo = mid + 1; else hi = mid; }
        return lo;
    };
    int lo = lb(g), hi = lb(g + 1);
    int len = hi - lo;
    int per = (len + 3) >> 2;
    int s0 = lo + seg * per;
    int s1 = s0 + per; if (s1 > hi) s1 = hi;
    float acc[8] = {};
    for (int r = s0 + rl; r < s1; r += 8) {
        size_t base = (size_t)r * HDIM + cg * 8;
        u16x8 a = *(const u16x8*)((const unsigned short*)x1 + base);
        u16x8 b = *(const u16x8*)((const unsigned short*)x2 + base);
        u16x8 c = *(const u16x8*)((const unsigned short*)x3 + base);
#pragma unroll
        for (int j = 0; j < 8; ++j)
            acc[j] += bf2f(a[j]) + bf2f(b[j]) + bf2f(c[j]);
    }
#pragma unroll
    for (int j = 0; j < 8; ++j) spool[rl][cg * 8 + j] = acc[j];
    __syncthreads();
    float s = 0.f;
#pragma unroll
    for (int r2 = 0; r2 < 8; ++r2) s += spool[r2][t];
    partial[(size_t)(seg * B + g) * HDIM + t] = s;
}

// classifier: sum 4 partials, divide by count (binary search), 2-layer MLP.
__global__ __launch_bounds__(256) void k_cls(const float* __restrict__ partial,
                                             const int* __restrict__ batch,
                                             const float* __restrict__ cw1,
                                             const float* __restrict__ cb1,
                                             const float* __restrict__ cw2,
                                             const float* __restrict__ cb2,
                                             float* __restrict__ out,
                                             int n, int B, int C) {
    __shared__ float sp[HDIM];
    __shared__ float sh[H2];
    int g = blockIdx.x, t = threadIdx.x;
    auto lb = [&](int key) {
        int lo = 0, hi = n;
        while (lo < hi) { int mid = (lo + hi) >> 1; if (batch[mid] < key) lo = mid + 1; else hi = mid; }
        return lo;
    };
    int lo = lb(g), hi = lb(g + 1);
    int cnt = hi - lo; if (cnt < 1) cnt = 1;
    float s = 0.f;
#pragma unroll
    for (int seg = 0; seg < 4; ++seg)
        s += partial[(size_t)(seg * B + g) * HDIM + t];
    sp[t] = s / (float)cnt;
    __syncthreads();
    if (t < H2) {
        float a = cb1[t];
        for (int h = 0; h < HDIM; ++h) a += sp[h] * cw1[h * H2 + t];
        sh[t] = fmaxf(a, 0.f);
    }
    __syncthreads();
    if (t < C) {
        float o = cb2[t];
        for (int j = 0; j < H2; ++j) o += sh[j] * cw2[j * C + t];
        out[g * C + t] = o;
    }
    if (g == 0 && t == 0) out[B * C] = 0.f;
}

// ---------------------------------------------------------------------------
extern "C" void kernel_launch(void* const* d_in, const int* in_sizes, int n_in,
                              void* d_out, int out_size, void* d_ws, size_t ws_size,
                              hipStream_t stream) {
    const int* x      = (const int*)d_in[0];
    const int* erow   = (const int*)d_in[1];
    const int* batch  = (const int*)d_in[2];
    const float* emb  = (const float*)d_in[3];
    const float* W1   = (const float*)d_in[4];
    const float* b1   = (const float*)d_in[5];
    const float* W2   = (const float*)d_in[6];
    const float* b2   = (const float*)d_in[7];
    const float* W3   = (const float*)d_in[8];
    const float* b3   = (const float*)d_in[9];
    const float* cw1  = (const float*)d_in[10];
    const float* cb1  = (const float*)d_in[11];
    const float* cw2  = (const float*)d_in[12];
    const float* cb2  = (const float*)d_in[13];
    float* out = (float*)d_out;

    const int N = in_sizes[2];
    const int E = in_sizes[1] / 2;
    const int F = in_sizes[0] / N;
    const int V = in_sizes[3] / (F * HDIM);
    const int C = in_sizes[13];
    const int B = (out_size - 1) / C;
    const int* ecol = erow + E;
    const int EMBTOT = F * V * HDIM;

    char* w = (char*)d_ws;
    auto carve = [&](size_t bytes) {
        void* p = (void*)w;
        w += (bytes + 255) & ~(size_t)255;
        return p;
    };
    short* P0     = (short*)carve((size_t)N * HDIM * 2);   // h0, later x3
    short* P1     = (short*)carve((size_t)N * HDIM * 2);   // x1
    short* P2     = (short*)carve((size_t)N * HDIM * 2);   // x2
    short* mS     = (short*)carve((size_t)N * HDIM * 2);   // GEMM output (messages)
    short* embb   = (short*)carve((size_t)EMBTOT * 2);
    short* Wt1    = (short*)carve((size_t)HDIM * HDIM * 2);
    short* Wt2    = (short*)carve((size_t)HDIM * HDIM * 2);
    short* Wt3    = (short*)carve((size_t)HDIM * HDIM * 2);
    float* partial= (float*)carve((size_t)4 * B * HDIM * 4);
    float* dis    = (float*)carve((size_t)N * 4);
    int* deg0     = (int*)carve((size_t)N * 4);
    int* ptr      = (int*)carve((size_t)N * 4);
    int* cursor   = (int*)carve((size_t)N * 4);
    int* bsum     = (int*)carve(1024 * 4);
    int* csr      = (int*)carve((size_t)E * 4);

    int nblk = (N + 255) / 256;

    hipMemsetAsync(deg0, 0, (size_t)N * 4, stream);
    hipMemsetAsync(cursor, 0, (size_t)N * 4, stream);
    k_deg<<<(E + 255) / 256, 256, 0, stream>>>(ecol, deg0, E);
    k_scan1<<<nblk, 256, 0, stream>>>(deg0, ptr, bsum, N);
    k_scan2<<<1, 512, 0, stream>>>(bsum, nblk);
    k_scan3<<<nblk, 256, 0, stream>>>(ptr, bsum, deg0, dis, N);
    int nch = (E + 2047) / 2048;
    k_fill8<<<nch * 8, 256, 0, stream>>>(erow, ecol, ptr, cursor, csr, E);
    k_emb<<<(EMBTOT + 255) / 256, 256, 0, stream>>>(emb, embb, EMBTOT);
    dim3 wgrid(HDIM, 3);
    k_wt3<<<wgrid, 256, 0, stream>>>(W1, W2, W3, Wt1, Wt2, Wt3);
    k_atom<<<(N + 3) / 4, 256, 0, stream>>>(x, embb, P0, N, F, V);

    int ggrid = (N + 63) / 64;
    int agrid = (N + 3) / 4;

    k_gemm<<<ggrid, 256, 0, stream>>>(P0, Wt1, mS, N);
    k_agg<<<agrid, 256, 0, stream>>>(mS, csr, ptr, deg0, dis, b1, P1, N);
    k_gemm<<<ggrid, 256, 0, stream>>>(P1, Wt2, mS, N);
    k_agg<<<agrid, 256, 0, stream>>>(mS, csr, ptr, deg0, dis, b2, P2, N);
    k_gemm<<<ggrid, 256, 0, stream>>>(P2, Wt3, mS, N);
    k_agg<<<agrid, 256, 0, stream>>>(mS, csr, ptr, deg0, dis, b3, P0, N);

    dim3 pgrid(B, 4);
    k_pool<<<pgrid, 256, 0, stream>>>(P1, P2, P0, batch, partial, N, B);
    k_cls<<<B, 256, 0, stream>>>(partial, batch, cw1, cb1, cw2, cb2, out, N, B, C);
}